// Round 1
// baseline (231.509 us; speedup 1.0000x reference)
//
#include <hip/hip_runtime.h>
#include <hip/hip_bf16.h>

// CrossChannelAttention: B=2, C=64, H=W=96 -> N=9216 pixels, NF=192, RD=24.
// out[b,c,n] = rgb_in[b,c,n] + sum_k v[b,c,k]*softmax_k(q[b,n,:].k[b,k,:])
// 3 kernels: weight prep (bf16, log2e folded into Wq), qkv GEMM (MFMA),
// fused flash attention (swapped QK^T bf16 + fp8 P.V).

#define NPIX 9216
#define NTILE 144   // 64-row q-tiles per batch
#define NKT 144     // 64-key tiles

typedef unsigned short ushort_t;
typedef __attribute__((ext_vector_type(8))) short bf16x8;
typedef __attribute__((ext_vector_type(16))) float f32x16;
typedef __attribute__((ext_vector_type(4))) unsigned int uint4v;

__device__ inline ushort_t f2bf(float x) {
  __hip_bfloat16 h = __float2bfloat16(x);
  return *reinterpret_cast<ushort_t*>(&h);
}
__device__ inline float fast_exp2(float x) {
#if __has_builtin(__builtin_amdgcn_exp2f)
  return __builtin_amdgcn_exp2f(x);
#else
  return exp2f(x);
#endif
}

// ---------------- kernel 0: pack W_cat (256x192 bf16) + bias_cat ----------
__global__ void k_prep(const float* __restrict__ Wq, const float* __restrict__ bq,
                       const float* __restrict__ Wk, const float* __restrict__ bk,
                       const float* __restrict__ Wv, const float* __restrict__ bv,
                       ushort_t* __restrict__ Wbf, float* __restrict__ bias) {
  const float LOG2E = 1.4426950408889634f;
  int idx = blockIdx.x * 256 + threadIdx.x;
  if (idx < 256 * 192) {
    int o = idx / 192, c = idx % 192;
    float v = 0.f;
    if (o < 24) v = Wq[o * 192 + c] * LOG2E;
    else if (o < 48) v = Wk[(o - 24) * 192 + c];
    else if (o < 240) v = Wv[(o - 48) * 192 + c];
    Wbf[idx] = f2bf(v);
  }
  if (idx < 256) {
    float v = 0.f;
    if (idx < 24) v = bq[idx] * LOG2E;
    else if (idx < 48) v = bk[idx - 24];
    else if (idx < 240) v = bv[idx - 48];
    bias[idx] = v;
  }
}

// ---------------- kernel 1: qkv = W_cat . rgb  (MFMA 32x32x16 bf16) -------
// q_ws,k_ws: (B,N,32) bf16 rows (cols 24..31 zeroed). v_ws: (B,192,N) fp8 e4m3.
__global__ __launch_bounds__(256, 2)
void k_qkv(const float* __restrict__ rIn, const float* __restrict__ gIn,
           const float* __restrict__ bIn,
           const ushort_t* __restrict__ Wbf, const float* __restrict__ bias,
           ushort_t* __restrict__ q_ws, ushort_t* __restrict__ k_ws,
           unsigned char* __restrict__ v_ws) {
  __shared__ __align__(16) ushort_t lds[64 * 200];  // [n][c] transposed tile, pad 200
  int blk = blockIdx.x;
  int bb = blk / NTILE, nt = blk % NTILE;
  int n0 = nt * 64;
  int t = threadIdx.x;
  {  // stage rgb tile transposed: lds[n][c] (bf16 pairs along c)
    int n4 = (t & 15) * 4;
    int c0 = (t >> 4) * 2;
#pragma unroll
    for (int it = 0; it < 6; ++it) {
      int c = c0 + it * 32;  // even
      int color = c >> 6, cw = c & 63;
      const float* base = color == 0 ? rIn : (color == 1 ? gIn : bIn);
      const float* p0 = base + ((size_t)bb * 64 + cw) * NPIX + n0 + n4;
      float4 va = *(const float4*)p0;
      float4 vb = *(const float4*)(p0 + NPIX);  // row c+1, same color block
      const float* ap = (const float*)&va;
      const float* bp = (const float*)&vb;
#pragma unroll
      for (int j = 0; j < 4; ++j) {
        unsigned u = ((unsigned)f2bf(bp[j]) << 16) | (unsigned)f2bf(ap[j]);
        *(unsigned*)((char*)lds + (size_t)((n4 + j) * 200 + c) * 2) = u;
      }
    }
  }
  __syncthreads();
  int w = t >> 6, l = t & 63, lo = l & 31, h = l >> 5;
  f32x16 acc[2][2] = {{{}, {}}, {{}, {}}};
  int oG[2] = {(2 * w + 0) * 32 + lo, (2 * w + 1) * 32 + lo};
#pragma unroll 1
  for (int cc = 0; cc < 12; ++cc) {
    bf16x8 af[2], bfr[2];
#pragma unroll
    for (int i = 0; i < 2; ++i)
      af[i] = *(const bf16x8*)((const char*)Wbf + (size_t)oG[i] * 384 + cc * 32 + 16 * h);
#pragma unroll
    for (int ns = 0; ns < 2; ++ns)
      bfr[ns] = *(const bf16x8*)((const char*)lds + (size_t)(ns * 32 + lo) * 400 + cc * 32 + 16 * h);
#pragma unroll
    for (int i = 0; i < 2; ++i)
#pragma unroll
      for (int ns = 0; ns < 2; ++ns)
        acc[i][ns] = __builtin_amdgcn_mfma_f32_32x32x16_bf16(af[i], bfr[ns], acc[i][ns], 0, 0, 0);
  }
  // epilogue: D[n-row, o-col]; col = lane&31, row = (r&3)+8*(r>>2)+4*h
#pragma unroll
  for (int i = 0; i < 2; ++i) {
    int o = oG[i];
    float bv = bias[o];
#pragma unroll
    for (int ns = 0; ns < 2; ++ns) {
      if (o < 32) {
#pragma unroll
        for (int r = 0; r < 16; ++r) {
          int n = n0 + ns * 32 + (r & 3) + 8 * (r >> 2) + 4 * h;
          ushort_t val = (o < 24) ? f2bf(acc[i][ns][r] + bv) : (ushort_t)0;
          q_ws[((size_t)bb * NPIX + n) * 32 + o] = val;
        }
      }
      if (o >= 24 && o < 56) {
        int kc = o - 24;
#pragma unroll
        for (int r = 0; r < 16; ++r) {
          int n = n0 + ns * 32 + (r & 3) + 8 * (r >> 2) + 4 * h;
          ushort_t val = (o < 48) ? f2bf(acc[i][ns][r] + bv) : (ushort_t)0;
          k_ws[((size_t)bb * NPIX + n) * 32 + kc] = val;
        }
      }
      if (o >= 48 && o < 240) {
        int vc = o - 48;
#pragma unroll
        for (int g2 = 0; g2 < 4; ++g2) {
          int r = g2 * 4;
          int n = n0 + ns * 32 + 8 * g2 + 4 * h;  // 4 consecutive n
          unsigned wd = (unsigned)__builtin_amdgcn_cvt_pk_fp8_f32(
              acc[i][ns][r] + bv, acc[i][ns][r + 1] + bv, 0, false);
          wd = (unsigned)__builtin_amdgcn_cvt_pk_fp8_f32(
              acc[i][ns][r + 2] + bv, acc[i][ns][r + 3] + bv, (int)wd, true);
          *(unsigned*)(v_ws + ((size_t)bb * 192 + vc) * NPIX + n) = wd;
        }
      }
    }
  }
}

// ---------------- kernel 2: fused flash attention -------------------------
// 4 waves: wq=w>>1 (q rows 32/wave), wc=w&1 (96 channels/wave).
// S' = mfma(K,Q): lane holds P-row for q=lane&31 (16 of 32 keys per half).
// P->fp8 A-frags via cvt_pk_fp8 + half-wave swap; PV = mfma fp8xfp8.
__global__ __launch_bounds__(256, 2)
void k_attn(const ushort_t* __restrict__ q_ws, const ushort_t* __restrict__ k_ws,
            const unsigned char* __restrict__ v_ws,
            const float* __restrict__ rIn, const float* __restrict__ gIn,
            const float* __restrict__ bIn, float* __restrict__ out) {
  // LDS: V dbuf [192][96B-row, 4 swizzled 16B pairs] @0/@18432; K dbuf [64][64B] @36864/@40960.
  // Epilogue overlays O[64][193] f32 (49408 B).
  __shared__ __align__(16) char smem[49408];
  int id = blockIdx.x;
  int swz = (id & 7) * 36 + (id >> 3);  // XCDs 0-3 -> batch 0, 4-7 -> batch 1
  int bb = swz / NTILE, qt = swz % NTILE;
  int q0 = qt * 64;
  int t = threadIdx.x, w = t >> 6, l = t & 63, lo = l & 31, h = l >> 5;
  int wq = w >> 1, wc = w & 1;
  const char* qb = (const char*)q_ws + (size_t)bb * NPIX * 64;
  const char* kb = (const char*)k_ws + (size_t)bb * NPIX * 64;
  const char* vb = (const char*)v_ws + (size_t)bb * 192 * NPIX;

  bf16x8 qf0, qf1;  // Q B-frags (d 0-15 / 16-31), q row = q0+wq*32+lo
  {
    const char* qrow = qb + (size_t)(q0 + wq * 32 + lo) * 64;
    qf0 = *(const bf16x8*)(qrow + 16 * h);
    qf1 = *(const bf16x8*)(qrow + 32 + 16 * h);
  }
  // staging offsets (constant per lane)
  int vG[3], vW[3];
#pragma unroll
  for (int i = 0; i < 3; ++i) {
    int idx = (w * 3 + i) * 64 + l;  // 768 16B-chunks = 192c x 4 pairs
    int c = idx >> 2, pr = idx & 3;
    vG[i] = c * NPIX + pr * 16;
    vW[i] = c * 96 + 16 * (pr ^ ((c >> 2) & 3));
  }
  int krow = w * 16 + (l >> 2), kslot = l & 3;
  int kG = krow * 64 + kslot * 16;
  int kW = krow * 64 + 16 * (kslot ^ (krow & 3));

  {  // prologue: stage tile 0 into buffers 0
    uint4v v0 = *(const uint4v*)(vb + vG[0]);
    uint4v v1 = *(const uint4v*)(vb + vG[1]);
    uint4v v2 = *(const uint4v*)(vb + vG[2]);
    uint4v kk = *(const uint4v*)(kb + kG);
    *(uint4v*)(smem + vW[0]) = v0;
    *(uint4v*)(smem + vW[1]) = v1;
    *(uint4v*)(smem + vW[2]) = v2;
    *(uint4v*)(smem + 36864 + kW) = kk;
  }
  __syncthreads();

  f32x16 oacc[3] = {{}, {}, {}};
  float lsum = 0.f;

#pragma unroll 1
  for (int tt = 0; tt < NKT; ++tt) {
    int par = tt & 1;
    const char* vbuf = smem + par * 18432;
    const char* kbuf = smem + 36864 + par * 4096;
    char* vdst = smem + (par ^ 1) * 18432;
    char* kdst = smem + 36864 + (par ^ 1) * 4096;
    uint4v vr0, vr1, vr2, kr;
    bool st = (tt + 1 < NKT);
    if (st) {  // issue next-tile loads early (hide HBM/L2 latency under MFMA)
      const char* vsrc = vb + (tt + 1) * 64;
      vr0 = *(const uint4v*)(vsrc + vG[0]);
      vr1 = *(const uint4v*)(vsrc + vG[1]);
      vr2 = *(const uint4v*)(vsrc + vG[2]);
      kr = *(const uint4v*)(kb + (size_t)(tt + 1) * 4096 + kG);
    }
#pragma unroll
    for (int ka = 0; ka < 2; ++ka) {  // two 32-key sub-tiles
      int row = ka * 32 + lo;
      const char* kp = kbuf + row * 64;
      bf16x8 kf0 = *(const bf16x8*)(kp + 16 * (h ^ (row & 3)));
      bf16x8 kf1 = *(const bf16x8*)(kp + 16 * ((2 + h) ^ (row & 3)));
      f32x16 s = {};
      s = __builtin_amdgcn_mfma_f32_32x32x16_bf16(kf0, qf0, s, 0, 0, 0);
      s = __builtin_amdgcn_mfma_f32_32x32x16_bf16(kf1, qf1, s, 0, 0, 0);
      float p[16];
#pragma unroll
      for (int r = 0; r < 16; ++r) { p[r] = fast_exp2(s[r]); lsum += p[r]; }
#pragma unroll
      for (int ch = 0; ch < 2; ++ch) {  // 16-key chunks
        const float* pp = p + ch * 8;
        unsigned ulo = (unsigned)__builtin_amdgcn_cvt_pk_fp8_f32(pp[0], pp[1], 0, false);
        ulo = (unsigned)__builtin_amdgcn_cvt_pk_fp8_f32(pp[2], pp[3], (int)ulo, true);
        unsigned uhi = (unsigned)__builtin_amdgcn_cvt_pk_fp8_f32(pp[4], pp[5], 0, false);
        uhi = (unsigned)__builtin_amdgcn_cvt_pk_fp8_f32(pp[6], pp[7], (int)uhi, true);
        unsigned slo = __shfl_xor(ulo, 32);
        unsigned shi = __shfl_xor(uhi, 32);
        unsigned a0 = (h == 0) ? ulo : shi;  // keys 8h+0..3
        unsigned a1 = (h == 0) ? slo : uhi;  // keys 8h+4..7
        long A = (long)(((unsigned long long)a1 << 32) | a0);
        int pairIdx = ka * 2 + ch;
#pragma unroll
        for (int ct = 0; ct < 3; ++ct) {
          int c = wc * 96 + ct * 32 + lo;
          const char* vp = vbuf + c * 96 + 16 * (pairIdx ^ ((c >> 2) & 3)) + 8 * h;
          long Bv = *(const long*)vp;
          oacc[ct] = __builtin_amdgcn_mfma_f32_32x32x16_fp8_fp8(A, Bv, oacc[ct], 0, 0, 0);
        }
      }
    }
    if (st) {  // late LDS writes into the free buffer
      *(uint4v*)(vdst + vW[0]) = vr0;
      *(uint4v*)(vdst + vW[1]) = vr1;
      *(uint4v*)(vdst + vW[2]) = vr2;
      *(uint4v*)(kdst + kW) = kr;
    }
    __syncthreads();
  }

  float ltot = lsum + __shfl_xor(lsum, 32);  // both halves hold l[q=lane&31]
  float rinv = 1.0f / ltot;
  float* OL = (float*)smem;  // overlay O[64][193]
#pragma unroll
  for (int ct = 0; ct < 3; ++ct) {
    int c = wc * 96 + ct * 32 + lo;
#pragma unroll
    for (int r = 0; r < 16; ++r) {
      int qr = (r & 3) + 8 * (r >> 2) + 4 * h;
      float sc = __shfl(rinv, qr);
      OL[(wq * 32 + qr) * 193 + c] = oacc[ct][r] * sc;
    }
  }
  __syncthreads();
  // coalesced residual-add + store: warp w handles channels w+4i, lanes along n
#pragma unroll 1
  for (int i = 0; i < 48; ++i) {
    int c = w + 4 * i;
    int color = c >> 6, cw = c & 63;
    const float* base = color == 0 ? rIn : (color == 1 ? gIn : bIn);
    float resid = base[((size_t)bb * 64 + cw) * NPIX + q0 + l];
    float val = OL[l * 193 + c] + resid;
    out[((size_t)color * 2 * 64 + (size_t)bb * 64 + cw) * NPIX + q0 + l] = val;
  }
}

// ---------------- launcher -------------------------------------------------
extern "C" void kernel_launch(void* const* d_in, const int* in_sizes, int n_in,
                              void* d_out, int out_size, void* d_ws, size_t ws_size,
                              hipStream_t stream) {
  const float* r  = (const float*)d_in[0];
  const float* g  = (const float*)d_in[1];
  const float* b  = (const float*)d_in[2];
  const float* Wq = (const float*)d_in[3];
  const float* bq = (const float*)d_in[4];
  const float* Wk = (const float*)d_in[5];
  const float* bk = (const float*)d_in[6];
  const float* Wv = (const float*)d_in[7];
  const float* bv = (const float*)d_in[8];

  char* ws = (char*)d_ws;
  ushort_t* Wbf = (ushort_t*)(ws);                       //  98304 B
  float* bias   = (float*)(ws + 98304);                  //   1024 B
  ushort_t* q_ws = (ushort_t*)(ws + 99328);              // 1179648 B
  ushort_t* k_ws = (ushort_t*)(ws + 99328 + 1179648);    // 1179648 B
  unsigned char* v_ws = (unsigned char*)(ws + 99328 + 2 * 1179648);  // 3538944 B

  k_prep<<<192, 256, 0, stream>>>(Wq, bq, Wk, bk, Wv, bv, Wbf, bias);
  k_qkv<<<2 * NTILE, 256, 0, stream>>>(r, g, b, Wbf, bias, q_ws, k_ws, v_ws);
  k_attn<<<2 * NTILE, 256, 0, stream>>>(q_ws, k_ws, v_ws, r, g, b, (float*)d_out);
}

// Round 2
// 152.471 us; speedup vs baseline: 1.5184x; 1.5184x over previous
//
#include <hip/hip_runtime.h>
#include <hip/hip_bf16.h>

// CrossChannelAttention: B=2, C=64, H=W=96 -> N=9216, NF=192, RD=24.
// Flash-decoding split: k_qkv (MFMA projections) -> k_attn (S key-segments,
// unnormalized O partials + lsum partials) -> k_comb (sum/normalize/residual).
// k_attn: 4 waves = 4 q-subtiles of 32 (Q-tile 128), each wave does all 192
// channels -> 1 exp per score (round-1 layout computed each score twice).

#define NPIX 9216
#define NKT 144     // 64-key tiles total
#define QTILES 72   // 128-row q-tiles per batch

typedef unsigned short ushort_t;
typedef __attribute__((ext_vector_type(8))) short bf16x8;
typedef __attribute__((ext_vector_type(16))) float f32x16;
typedef __attribute__((ext_vector_type(4))) unsigned int uint4v;
typedef __attribute__((ext_vector_type(2))) unsigned long long ulong2v;

__device__ inline ushort_t f2bf(float x) {
  __hip_bfloat16 h = __float2bfloat16(x);
  return *reinterpret_cast<ushort_t*>(&h);
}
__device__ inline float bf2f(ushort_t u) {
  unsigned v = ((unsigned)u) << 16;
  return *reinterpret_cast<float*>(&v);
}
__device__ inline float fast_exp2(float x) {
#if __has_builtin(__builtin_amdgcn_exp2f)
  return __builtin_amdgcn_exp2f(x);
#else
  return exp2f(x);
#endif
}

// ---------------- kernel 0: pack W_cat (256x192 bf16) + bias_cat ----------
__global__ void k_prep(const float* __restrict__ Wq, const float* __restrict__ bq,
                       const float* __restrict__ Wk, const float* __restrict__ bk,
                       const float* __restrict__ Wv, const float* __restrict__ bv,
                       ushort_t* __restrict__ Wbf, float* __restrict__ bias) {
  const float LOG2E = 1.4426950408889634f;
  int idx = blockIdx.x * 256 + threadIdx.x;
  if (idx < 256 * 192) {
    int o = idx / 192, c = idx % 192;
    float v = 0.f;
    if (o < 24) v = Wq[o * 192 + c] * LOG2E;
    else if (o < 48) v = Wk[(o - 24) * 192 + c];
    else if (o < 240) v = Wv[(o - 48) * 192 + c];
    Wbf[idx] = f2bf(v);
  }
  if (idx < 256) {
    float v = 0.f;
    if (idx < 24) v = bq[idx] * LOG2E;
    else if (idx < 48) v = bk[idx - 24];
    else if (idx < 240) v = bv[idx - 48];
    bias[idx] = v;
  }
}

// ---------------- kernel 1: qkv = W_cat . rgb  (MFMA 32x32x16 bf16) -------
// q_ws,k_ws: (B,N,32) bf16 rows (cols 24..31 zeroed). v_ws: (B,192,N) fp8 e4m3.
__global__ __launch_bounds__(256, 2)
void k_qkv(const float* __restrict__ rIn, const float* __restrict__ gIn,
           const float* __restrict__ bIn,
           const ushort_t* __restrict__ Wbf, const float* __restrict__ bias,
           ushort_t* __restrict__ q_ws, ushort_t* __restrict__ k_ws,
           unsigned char* __restrict__ v_ws) {
  __shared__ __align__(16) ushort_t lds[64 * 200];  // [n][c] transposed tile
  int blk = blockIdx.x;
  int bb = blk / NKT, nt = blk % NKT;
  int n0 = nt * 64;
  int t = threadIdx.x;
  {
    int n4 = (t & 15) * 4;
    int c0 = (t >> 4) * 2;
#pragma unroll
    for (int it = 0; it < 6; ++it) {
      int c = c0 + it * 32;
      int color = c >> 6, cw = c & 63;
      const float* base = color == 0 ? rIn : (color == 1 ? gIn : bIn);
      const float* p0 = base + ((size_t)bb * 64 + cw) * NPIX + n0 + n4;
      float4 va = *(const float4*)p0;
      float4 vb = *(const float4*)(p0 + NPIX);
      const float* ap = (const float*)&va;
      const float* bp = (const float*)&vb;
#pragma unroll
      for (int j = 0; j < 4; ++j) {
        unsigned u = ((unsigned)f2bf(bp[j]) << 16) | (unsigned)f2bf(ap[j]);
        *(unsigned*)((char*)lds + (size_t)((n4 + j) * 200 + c) * 2) = u;
      }
    }
  }
  __syncthreads();
  int w = t >> 6, l = t & 63, lo = l & 31, h = l >> 5;
  f32x16 acc[2][2] = {{{}, {}}, {{}, {}}};
  int oG[2] = {(2 * w + 0) * 32 + lo, (2 * w + 1) * 32 + lo};
#pragma unroll 1
  for (int cc = 0; cc < 12; ++cc) {
    bf16x8 af[2], bfr[2];
#pragma unroll
    for (int i = 0; i < 2; ++i)
      af[i] = *(const bf16x8*)((const char*)Wbf + (size_t)oG[i] * 384 + cc * 32 + 16 * h);
#pragma unroll
    for (int ns = 0; ns < 2; ++ns)
      bfr[ns] = *(const bf16x8*)((const char*)lds + (size_t)(ns * 32 + lo) * 400 + cc * 32 + 16 * h);
#pragma unroll
    for (int i = 0; i < 2; ++i)
#pragma unroll
      for (int ns = 0; ns < 2; ++ns)
        acc[i][ns] = __builtin_amdgcn_mfma_f32_32x32x16_bf16(af[i], bfr[ns], acc[i][ns], 0, 0, 0);
  }
#pragma unroll
  for (int i = 0; i < 2; ++i) {
    int o = oG[i];
    float bv = bias[o];
#pragma unroll
    for (int ns = 0; ns < 2; ++ns) {
      if (o < 32) {
#pragma unroll
        for (int r = 0; r < 16; ++r) {
          int n = n0 + ns * 32 + (r & 3) + 8 * (r >> 2) + 4 * h;
          ushort_t val = (o < 24) ? f2bf(acc[i][ns][r] + bv) : (ushort_t)0;
          q_ws[((size_t)bb * NPIX + n) * 32 + o] = val;
        }
      }
      if (o >= 24 && o < 56) {
        int kc = o - 24;
#pragma unroll
        for (int r = 0; r < 16; ++r) {
          int n = n0 + ns * 32 + (r & 3) + 8 * (r >> 2) + 4 * h;
          ushort_t val = (o < 48) ? f2bf(acc[i][ns][r] + bv) : (ushort_t)0;
          k_ws[((size_t)bb * NPIX + n) * 32 + kc] = val;
        }
      }
      if (o >= 48 && o < 240) {
        int vc = o - 48;
#pragma unroll
        for (int g2 = 0; g2 < 4; ++g2) {
          int r = g2 * 4;
          int n = n0 + ns * 32 + 8 * g2 + 4 * h;
          unsigned wd = (unsigned)__builtin_amdgcn_cvt_pk_fp8_f32(
              acc[i][ns][r] + bv, acc[i][ns][r + 1] + bv, 0, false);
          wd = (unsigned)__builtin_amdgcn_cvt_pk_fp8_f32(
              acc[i][ns][r + 2] + bv, acc[i][ns][r + 3] + bv, (int)wd, true);
          *(unsigned*)(v_ws + ((size_t)bb * 192 + vc) * NPIX + n) = wd;
        }
      }
    }
  }
}

// ---------------- kernel 2: flash attention, one key segment --------------
// LDS: V dbuf [8 kc][192 c][8B] @0/@12288 (XOR swizzle kc*16);
//      K dbuf [4 d8][64 row][16B] @24576/@28672 (XOR swizzle d8*16).
// Epilogue overlays OL[192][36] f32 (27648 B) to transpose partials to [c][n].
__global__ __launch_bounds__(256, 3)
void k_attn(const ushort_t* __restrict__ q_ws, const ushort_t* __restrict__ k_ws,
            const unsigned char* __restrict__ v_ws,
            ushort_t* __restrict__ opart, float* __restrict__ lpart,
            int S, int ktPer) {
  __shared__ __align__(16) char smem[32768];
  int id = blockIdx.x;
  int twoS = 2 * S;
  int g = id % twoS, qt = id / twoS;   // id%8 ~ XCD: all blocks of a segment share an XCD's L2
  int bb = g / S, sg = g % S;
  int q0 = qt * 128;
  int t = threadIdx.x, w = t >> 6, l = t & 63, lo = l & 31, h = l >> 5;
  const char* qb = (const char*)q_ws + (size_t)bb * NPIX * 64;
  const char* kb = (const char*)k_ws + (size_t)bb * NPIX * 64;
  const unsigned char* vb = v_ws + (size_t)bb * 192 * NPIX;

  bf16x8 qf0, qf1;  // Q B-frags, q row = q0 + w*32 + lo
  {
    const char* qrow = qb + (size_t)(q0 + w * 32 + lo) * 64;
    qf0 = *(const bf16x8*)(qrow + 16 * h);
    qf1 = *(const bf16x8*)(qrow + 32 + 16 * h);
  }
  // staging maps (per-thread constants)
  int vG[3], vA0[3], vA1[3];
#pragma unroll
  for (int i = 0; i < 3; ++i) {
    int idx = i * 256 + t;
    int c = idx >> 2, pr = idx & 3;
    vG[i] = c * NPIX + pr * 16;
    int kc0 = 2 * pr, kc1 = 2 * pr + 1;
    vA0[i] = kc0 * 1536 + ((c * 8) ^ (kc0 * 16));
    vA1[i] = kc1 * 1536 + ((c * 8) ^ (kc1 * 16));
  }
  int krow = t >> 2, kslot = t & 3;
  int kG = krow * 64 + kslot * 16;
  int kW = kslot * 1024 + ((krow * 16) ^ (kslot * 16));
  // read-address constants
  int lo8 = lo * 8, lo16 = lo * 16;
  int xk0 = h * 1024 + (lo16 ^ (h * 16));
  int xk1 = (2 + h) * 1024 + (lo16 ^ ((2 + h) * 16));
  int xv[4];
#pragma unroll
  for (int j = 0; j < 4; ++j) { int kc = 2 * j + h; xv[j] = kc * 1536 + (lo8 ^ (kc * 16)); }

  int tt0 = sg * ktPer;
  {  // prologue: stage tile tt0 into buffers 0
    const unsigned char* vsrc = vb + (size_t)tt0 * 64;
#pragma unroll
    for (int i = 0; i < 3; ++i) {
      ulong2v v = *(const ulong2v*)(vsrc + vG[i]);
      *(unsigned long long*)(smem + vA0[i]) = v.x;
      *(unsigned long long*)(smem + vA1[i]) = v.y;
    }
    uint4v kk = *(const uint4v*)(kb + (size_t)tt0 * 4096 + kG);
    *(uint4v*)(smem + 24576 + kW) = kk;
  }
  __syncthreads();

  f32x16 oacc[6] = {{}, {}, {}, {}, {}, {}};
  float lsum = 0.f;

#pragma unroll 1
  for (int it = 0; it < ktPer; ++it) {
    int par = it & 1;
    const char* vbuf = smem + par * 12288;
    const char* kbuf = smem + 24576 + par * 4096;
    char* vdst = smem + (par ^ 1) * 12288;
    char* kdst = smem + 24576 + (par ^ 1) * 4096;
    ulong2v vr[3]; uint4v kr;
    bool st = (it + 1 < ktPer);
    if (st) {  // issue next-tile global loads early (hide latency under MFMA)
      const unsigned char* vsrc = vb + (size_t)(tt0 + it + 1) * 64;
      vr[0] = *(const ulong2v*)(vsrc + vG[0]);
      vr[1] = *(const ulong2v*)(vsrc + vG[1]);
      vr[2] = *(const ulong2v*)(vsrc + vG[2]);
      kr = *(const uint4v*)(kb + (size_t)(tt0 + it + 1) * 4096 + kG);
    }
#pragma unroll
    for (int ka = 0; ka < 2; ++ka) {
      bf16x8 kf0 = *(const bf16x8*)(kbuf + ka * 512 + xk0);
      bf16x8 kf1 = *(const bf16x8*)(kbuf + ka * 512 + xk1);
      f32x16 s = {};
      s = __builtin_amdgcn_mfma_f32_32x32x16_bf16(kf0, qf0, s, 0, 0, 0);
      s = __builtin_amdgcn_mfma_f32_32x32x16_bf16(kf1, qf1, s, 0, 0, 0);
      float p[16];
#pragma unroll
      for (int r = 0; r < 16; ++r) { p[r] = fast_exp2(s[r]); lsum += p[r]; }
#pragma unroll
      for (int ch = 0; ch < 2; ++ch) {
        const float* pp = p + ch * 8;
        unsigned ulo = (unsigned)__builtin_amdgcn_cvt_pk_fp8_f32(pp[0], pp[1], 0, false);
        ulo = (unsigned)__builtin_amdgcn_cvt_pk_fp8_f32(pp[2], pp[3], (int)ulo, true);
        unsigned uhi = (unsigned)__builtin_amdgcn_cvt_pk_fp8_f32(pp[4], pp[5], 0, false);
        uhi = (unsigned)__builtin_amdgcn_cvt_pk_fp8_f32(pp[6], pp[7], (int)uhi, true);
        unsigned slo = __shfl_xor(ulo, 32);
        unsigned shi = __shfl_xor(uhi, 32);
        unsigned a0 = (h == 0) ? ulo : shi;
        unsigned a1 = (h == 0) ? slo : uhi;
        long A = (long)(((unsigned long long)a1 << 32) | a0);
        const char* vbase = vbuf + xv[ka * 2 + ch];
#pragma unroll
        for (int ct = 0; ct < 6; ++ct) {
          long Bv = *(const long*)(vbase + ct * 256);
          oacc[ct] = __builtin_amdgcn_mfma_f32_32x32x16_fp8_fp8(A, Bv, oacc[ct], 0, 0, 0);
        }
      }
    }
    if (st) {
      *(unsigned long long*)(vdst + vA0[0]) = vr[0].x;
      *(unsigned long long*)(vdst + vA1[0]) = vr[0].y;
      *(unsigned long long*)(vdst + vA0[1]) = vr[1].x;
      *(unsigned long long*)(vdst + vA1[1]) = vr[1].y;
      *(unsigned long long*)(vdst + vA0[2]) = vr[2].x;
      *(unsigned long long*)(vdst + vA1[2]) = vr[2].y;
      *(uint4v*)(kdst + kW) = kr;
    }
    __syncthreads();
  }

  // lsum partial: both halves hold l for q = lane&31 after swap-sum
  float ltot = lsum + __shfl_xor(lsum, 32);
  if (h == 0)
    lpart[(size_t)(sg * 2 + bb) * NPIX + q0 + w * 32 + lo] = ltot;

  // transpose O to [c][n] layout via LDS overlay OL[192][36], one wave at a time
  float* OL = (float*)smem;
  ushort_t* obase = opart + ((size_t)(sg * 2 + bb) * 192) * NPIX;
#pragma unroll 1
  for (int rd = 0; rd < 4; ++rd) {
    __syncthreads();
    if (w == rd) {
#pragma unroll
      for (int ct = 0; ct < 6; ++ct)
#pragma unroll
        for (int r = 0; r < 16; ++r) {
          int qr = (r & 3) + 8 * (r >> 2) + 4 * h;
          OL[(ct * 32 + lo) * 36 + qr] = oacc[ct][r];
        }
    }
    __syncthreads();
    int qq = (t & 7) * 4, c0 = t >> 3;
#pragma unroll
    for (int j = 0; j < 6; ++j) {
      int c = c0 + 32 * j;
      float4 vv = *(const float4*)&OL[c * 36 + qq];
      unsigned long long pk = (unsigned long long)f2bf(vv.x)
                            | ((unsigned long long)f2bf(vv.y) << 16)
                            | ((unsigned long long)f2bf(vv.z) << 32)
                            | ((unsigned long long)f2bf(vv.w) << 48);
      *(unsigned long long*)(obase + (size_t)c * NPIX + q0 + rd * 32 + qq) = pk;
    }
  }
}

// ---------------- kernel 3: combine partials + residual -------------------
// out[(color*2+bb)*64+cw][n] = resid + (sum_s O_s[c][n]) / (sum_s l_s[n])
__global__ __launch_bounds__(256, 8)
void k_comb(const ushort_t* __restrict__ opart, const float* __restrict__ lpart,
            const float* __restrict__ rIn, const float* __restrict__ gIn,
            const float* __restrict__ bIn, float* __restrict__ out, int S) {
  int tg = blockIdx.x * 256 + threadIdx.x;   // 442368 threads: (bb,c) x n8
  int n8 = tg % 1152, row = tg / 1152;       // row in [0,384)
  int bb = row / 192, c = row % 192;
  int n = n8 * 8;
  float acc[8] = {0.f, 0.f, 0.f, 0.f, 0.f, 0.f, 0.f, 0.f};
  float lt[8] = {0.f, 0.f, 0.f, 0.f, 0.f, 0.f, 0.f, 0.f};
#pragma unroll 1
  for (int sg = 0; sg < S; ++sg) {
    const ushort_t* p = opart + ((size_t)(sg * 2 + bb) * 192 + c) * NPIX + n;
    uint4v u = *(const uint4v*)p;
    const ushort_t* us = (const ushort_t*)&u;
#pragma unroll
    for (int j = 0; j < 8; ++j) acc[j] += bf2f(us[j]);
    const float* lp = lpart + (size_t)(sg * 2 + bb) * NPIX + n;
    float4 l0 = *(const float4*)lp;
    float4 l1 = *(const float4*)(lp + 4);
    lt[0] += l0.x; lt[1] += l0.y; lt[2] += l0.z; lt[3] += l0.w;
    lt[4] += l1.x; lt[5] += l1.y; lt[6] += l1.z; lt[7] += l1.w;
  }
  int color = c >> 6, cw = c & 63;
  const float* base = color == 0 ? rIn : (color == 1 ? gIn : bIn);
  const float* rp = base + ((size_t)bb * 64 + cw) * NPIX + n;
  float4 r0 = *(const float4*)rp;
  float4 r1 = *(const float4*)(rp + 4);
  float o[8];
  o[0] = r0.x + acc[0] / lt[0]; o[1] = r0.y + acc[1] / lt[1];
  o[2] = r0.z + acc[2] / lt[2]; o[3] = r0.w + acc[3] / lt[3];
  o[4] = r1.x + acc[4] / lt[4]; o[5] = r1.y + acc[5] / lt[5];
  o[6] = r1.z + acc[6] / lt[6]; o[7] = r1.w + acc[7] / lt[7];
  float* op = out + ((size_t)(color * 2 + bb) * 64 + cw) * NPIX + n;
  *(float4*)op = {o[0], o[1], o[2], o[3]};
  *(float4*)(op + 4) = {o[4], o[5], o[6], o[7]};
}

// ---------------- launcher -------------------------------------------------
extern "C" void kernel_launch(void* const* d_in, const int* in_sizes, int n_in,
                              void* d_out, int out_size, void* d_ws, size_t ws_size,
                              hipStream_t stream) {
  const float* r  = (const float*)d_in[0];
  const float* g  = (const float*)d_in[1];
  const float* b  = (const float*)d_in[2];
  const float* Wq = (const float*)d_in[3];
  const float* bq = (const float*)d_in[4];
  const float* Wk = (const float*)d_in[5];
  const float* bk = (const float*)d_in[6];
  const float* Wv = (const float*)d_in[7];
  const float* bv = (const float*)d_in[8];

  char* ws = (char*)d_ws;
  ushort_t* Wbf = (ushort_t*)(ws);                       //  98304 B
  float* bias   = (float*)(ws + 98304);                  //   1024 B
  ushort_t* q_ws = (ushort_t*)(ws + 99328);              // 1179648 B
  ushort_t* k_ws = (ushort_t*)(ws + 99328 + 1179648);    // 1179648 B
  unsigned char* v_ws = (unsigned char*)(ws + 99328 + 2 * 1179648);  // 3538944 B
  const size_t qkvEnd = 99328 + 2 * 1179648 + 3538944;   // 5997568
  const size_t perS = (size_t)2 * 192 * NPIX * 2 + (size_t)2 * NPIX * 4;  // 7151616

  int S = 8;
  while (S > 1 && qkvEnd + (size_t)S * perS > ws_size) S >>= 1;
  size_t opartSz = (size_t)S * 2 * 192 * NPIX * 2;
  ushort_t* opart = (ushort_t*)(ws + qkvEnd);
  float* lpart = (float*)(ws + qkvEnd + opartSz);

  k_prep<<<192, 256, 0, stream>>>(Wq, bq, Wk, bk, Wv, bv, Wbf, bias);
  k_qkv<<<2 * NKT, 256, 0, stream>>>(r, g, b, Wbf, bias, q_ws, k_ws, v_ws);
  k_attn<<<144 * S, 256, 0, stream>>>(q_ws, k_ws, v_ws, opart, lpart, S, NKT / S);
  k_comb<<<1728, 256, 0, stream>>>(opart, lpart, r, g, b, (float*)d_out, S);
}